// Round 8
// baseline (260.843 us; speedup 1.0000x reference)
//
#include <hip/hip_runtime.h>

// multihead self-attention: B=4 S=2048 D=1024 H=16 DK=64, causal, RoPE(theta=1e4)
// f16 pipeline, 4 dispatches:
//   cvt_all (x + 4 weights) | QKV = x*Wqkv^T (32x32x16 mfma, swizzled LDS, RoPE
//   fused in epilogue) | transposed flash (S^T=K*Q^T, O^T=V^T*P^T reg-P) | out gemm

#define D_MODEL 1024
#define NH      16
#define DKH     64
#define SEQ     2048
#define BATCH   4
#define M_ROWS  (BATCH * SEQ)   // 8192
#define SCALE_LOG2 0.180336875461f       // (1/sqrt(64)) * log2(e); applied to Q pre-MFMA
#define ROPE_L2    0.41524101186092029f  // log2(1e4)/32
#define L2_2PI     2.6514961294723187f   // log2(2*pi)

typedef _Float16 f16;
typedef _Float16 f16x8 __attribute__((ext_vector_type(8)));
typedef _Float16 f16x4 __attribute__((ext_vector_type(4)));
typedef _Float16 f16x2 __attribute__((ext_vector_type(2)));
typedef __fp16   fp16x2n __attribute__((ext_vector_type(2)));   // cvt_pkrtz native type
typedef float    f32x4  __attribute__((ext_vector_type(4)));
typedef float    f32x16 __attribute__((ext_vector_type(16)));
typedef unsigned short u16;
typedef unsigned int   u32;

__device__ __forceinline__ void glds16(const void* g, void* l) {
  __builtin_amdgcn_global_load_lds((const __attribute__((address_space(1))) void*)g,
                                   (__attribute__((address_space(3))) void*)l, 16, 0, 0);
}
__device__ __forceinline__ u32 pk(float a, float b) {
  union { fp16x2n h; u32 u; } c; c.h = __builtin_amdgcn_cvt_pkrtz(a, b); return c.u;
}

// ---------------- f32 -> f16 convert: x (8192 blocks) + 4 weights (1024 each) ----
__global__ void cvt_all(const float* __restrict__ x,
                        const float* __restrict__ w0, const float* __restrict__ w1,
                        const float* __restrict__ w2, const float* __restrict__ w3,
                        f16* __restrict__ xo, f16* __restrict__ o0, f16* __restrict__ o1,
                        f16* __restrict__ o2, f16* __restrict__ o3) {
  int blk = blockIdx.x;
  const float* src; f16* dst; int off;
  if (blk < 8192) { src = x; dst = xo; off = blk; }
  else {
    int t = blk - 8192; int w = t >> 10; off = t & 1023;
    switch (w) { case 0: src = w0; dst = o0; break;  case 1: src = w1; dst = o1; break;
                 case 2: src = w2; dst = o2; break;  default: src = w3; dst = o3; break; }
  }
  int i = (off * 256 + threadIdx.x) * 4;
  float4 v = *(const float4*)(src + i);
  uint2 o; o.x = pk(v.x, v.y); o.y = pk(v.z, v.w);
  *(uint2*)(dst + i) = o;
}

// ---- GEMM C[M,N] = A[M,K]*W[N,K]^T, 128x128 tile, BK=64, 32x32x16 mfma.
// LDS unpadded [128][64]; glds16 staging lane-linear with xor-swizzled global
// chunks (slot s of row r holds chunk s^(r&7)); frag reads spread all 32 banks.
// Wave = 64x64 out as 2x2 of 32x32; C layout col=lane&31, row=(reg&3)+8*(reg>>2)+4*hi.
// MODE 0: f32 out. MODE 1: f16 out split Q/K/V by n0; RoPE fused for Q,K
// (pair = adjacent cols = adjacent lanes -> shfl_xor(v,1); sin/cos in revolutions).
template<int MODE>
__global__ __launch_bounds__(256) void gemm_glds(const f16* __restrict__ A,
                                                 const f16* __restrict__ W,
                                                 void* __restrict__ C0,
                                                 void* __restrict__ C1,
                                                 void* __restrict__ C2,
                                                 const int* __restrict__ pos,
                                                 int K) {
  __shared__ f16 As[128][64];
  __shared__ f16 Bs[128][64];
  const int tid  = threadIdx.x;
  const int m0   = blockIdx.y * 128;
  const int n0   = blockIdx.x * 128;
  const int wave = tid >> 6, lane = tid & 63;
  const int l31  = lane & 31, hi = lane >> 5;
  const int wm = (wave >> 1) * 64, wn = (wave & 1) * 64;
  const int rx7 = l31 & 7;                   // (row&7) for all this lane's frag rows

  f32x16 acc[2][2];
#pragma unroll
  for (int i = 0; i < 2; ++i)
#pragma unroll
    for (int j = 0; j < 2; ++j) acc[i][j] = (f32x16)(0.f);

  for (int k0 = 0; k0 < K; k0 += 64) {
    if (k0) __syncthreads();
#pragma unroll
    for (int i = 0; i < 4; ++i) {            // 4 rounds x 256 lanes x 16B per buffer
      int ci  = i * 256 + tid;
      int row = ci >> 3, gc = (ci & 7) ^ (row & 7);
      glds16(A + (size_t)(m0 + row) * K + k0 + gc * 8,
             (char*)&As[0][0] + (size_t)(i * 256 + (tid & 192)) * 16);
      glds16(W + (size_t)(n0 + row) * K + k0 + gc * 8,
             (char*)&Bs[0][0] + (size_t)(i * 256 + (tid & 192)) * 16);
    }
    __syncthreads();                         // drains glds vmcnt for all waves
#pragma unroll
    for (int ks = 0; ks < 4; ++ks) {         // K-steps of 16
      const int slot = (ks * 2 + hi) ^ rx7;
      f16x8 af[2], bfr[2];
#pragma unroll
      for (int mi = 0; mi < 2; ++mi)
        af[mi] = *(const f16x8*)(&As[0][0] + (wm + mi * 32 + l31) * 64 + slot * 8);
#pragma unroll
      for (int ni = 0; ni < 2; ++ni)
        bfr[ni] = *(const f16x8*)(&Bs[0][0] + (wn + ni * 32 + l31) * 64 + slot * 8);
#pragma unroll
      for (int mi = 0; mi < 2; ++mi)
#pragma unroll
        for (int ni = 0; ni < 2; ++ni)
          acc[mi][ni] = __builtin_amdgcn_mfma_f32_32x32x16_f16(af[mi], bfr[ni], acc[mi][ni], 0, 0, 0);
    }
  }

  if (MODE == 1) {
    f16* dst; int nb;
    if (n0 < 1024)      { dst = (f16*)C0; nb = n0; }
    else if (n0 < 2048) { dst = (f16*)C1; nb = n0 - 1024; }
    else                { dst = (f16*)C2; nb = n0 - 2048; }
    if (n0 < 2048) {                         // Q or K: fused RoPE
      float invr[2], sgn[2];
#pragma unroll
      for (int ni = 0; ni < 2; ++ni) {
        int dk = (wn + ni * 32 + l31) & 63;
        invr[ni] = __builtin_amdgcn_exp2f(fmaf(-ROPE_L2, (float)(dk >> 1), -L2_2PI));
        sgn[ni]  = (dk & 1) ? 1.f : -1.f;
      }
#pragma unroll
      for (int mi = 0; mi < 2; ++mi)
#pragma unroll
        for (int reg = 0; reg < 16; ++reg) {
          int row = m0 + wm + mi * 32 + (reg & 3) + 8 * (reg >> 2) + 4 * hi;
          float ps = (float)pos[row & (SEQ - 1)];
#pragma unroll
          for (int ni = 0; ni < 2; ++ni) {
            float rev = __builtin_amdgcn_fractf(ps * invr[ni]);
            float sn = __builtin_amdgcn_sinf(rev);   // sin(2*pi*rev)
            float cs = __builtin_amdgcn_cosf(rev);
            float v = acc[mi][ni][reg];
            float p = __shfl_xor(v, 1);
            float ov = fmaf(p * sgn[ni], sn, v * cs);
            int col = nb + wn + ni * 32 + l31;
            dst[(size_t)row * 1024 + col] = (f16)ov;
          }
        }
    } else {                                 // V: plain
#pragma unroll
      for (int mi = 0; mi < 2; ++mi)
#pragma unroll
        for (int ni = 0; ni < 2; ++ni)
#pragma unroll
          for (int reg = 0; reg < 16; ++reg) {
            int row = m0 + wm + mi * 32 + (reg & 3) + 8 * (reg >> 2) + 4 * hi;
            int col = nb + wn + ni * 32 + l31;
            dst[(size_t)row * 1024 + col] = (f16)acc[mi][ni][reg];
          }
    }
  } else {
    float* dst = (float*)C0;
#pragma unroll
    for (int mi = 0; mi < 2; ++mi)
#pragma unroll
      for (int ni = 0; ni < 2; ++ni)
#pragma unroll
        for (int reg = 0; reg < 16; ++reg) {
          int row = m0 + wm + mi * 32 + (reg & 3) + 8 * (reg >> 2) + 4 * hi;
          int col = n0 + wn + ni * 32 + l31;
          dst[(size_t)row * 1024 + col] = acc[mi][ni][reg];
        }
  }
}

// ---------------- transposed causal flash attention ----------------
// grid (B*H, 32); block 256 = 4 waves. Block owns 64 q-rows; KV-tiles of 128 keys,
// wave w owns keys [kt+32w, kt+32w+32). S^T = K*Q^T (16x16x32_f16) with Q pre-scaled
// by SCALE_LOG2 -> p = exp2(c) (offset-free: constant factor cancels in O/l) ->
// P^T register-resident as B-operand of 16x16x16_f16: O^T += V^T * P^T.
// Ks: unpadded [128][64] via glds16, xor-swizzled source chunks.
// Vt: u32 [64][67]. End reduction: wave-pairs into two Red buffers (3 barriers).
__global__ __launch_bounds__(256, 3) void flash_attn(const f16* __restrict__ Q,
                                                     const f16* __restrict__ Kg,
                                                     const f16* __restrict__ Vg,
                                                     f16* __restrict__ O) {
  __shared__ char smem[38400];
  f16*  KsL         = (f16*)smem;                   // [128][64] key x dk (swizzled), 16 KB
  u32   (*Vt)[67]   = (u32(*)[67])(smem + 16384);   // [64 dk][67 key-pair], 17152 B
  float (*Red0)[66] = (float(*)[66])smem;           // [64 dk][66 q] waves 0,1 (aliases Ks)
  float (*Red1)[66] = (float(*)[66])(smem + 16896); // waves 2,3 (aliases Vt)
  float (*Lb)[17]   = (float(*)[17])(smem + 33792); // [64 q][17], cols 0..15 = wave*4+quad

  const int tid  = threadIdx.x;
  const int bh   = blockIdx.x;
  const int b    = bh >> 4, h = bh & 15;
  const int qblk = 31 - (int)blockIdx.y;          // longest first
  const int q0   = qblk * 64;
  const int wave = tid >> 6, lane = tid & 63;
  const int quad = lane >> 4, l16 = lane & 15;
  const int nkt  = (qblk + 2) >> 1;               // 128-key tiles covering q0+64 keys

  // Q B-frags (pre-scaled by SCALE_LOG2): B[k=dk][n=q] = Q[q=l16][dk=quad*8+j]
  f16x8 qf[4][2];
#pragma unroll
  for (int nt = 0; nt < 4; ++nt)
#pragma unroll
    for (int ks = 0; ks < 2; ++ks) {
      f16x8 qv = *(const f16x8*)(Q + ((size_t)(b * SEQ + q0 + nt * 16 + l16)) * D_MODEL
                                   + h * DKH + ks * 32 + quad * 8);
      qf[nt][ks] = qv * (f16)SCALE_LOG2;
    }

  f32x4 o[4][4];        // O^T partial: [dk-mtile][q-ntile], C layout dk=quad*4+r, q=l16
#pragma unroll
  for (int md = 0; md < 4; ++md)
#pragma unroll
    for (int nt = 0; nt < 4; ++nt) o[md][nt] = (f32x4){0.f, 0.f, 0.f, 0.f};
  float lacc[4] = {0.f, 0.f, 0.f, 0.f};

  const int kp = tid >> 3, dc = (tid & 7) * 8;    // V-transpose staging role

  for (int t = 0; t < nkt; ++t) {
    const int kt = t * 128;
    // V global loads early (keys 2kp,2kp+1 and 64+2kp,65+2kp; dk dc..dc+7)
    const f16* vb = Vg + ((size_t)(b * SEQ + kt + 2 * kp)) * D_MODEL + h * DKH + dc;
    uint4 v0 = *(const uint4*)vb;
    uint4 v1 = *(const uint4*)(vb + D_MODEL);
    uint4 v2 = *(const uint4*)(vb + 64 * D_MODEL);
    uint4 v3 = *(const uint4*)(vb + 65 * D_MODEL);

    if (t) __syncthreads();          // all waves done with prior Ks/Vt
    // K staging via glds16: LDS dest lane-linear, global chunk xor-swizzled
#pragma unroll
    for (int i = 0; i < 4; ++i) {
      int ci = i * 256 + tid;
      int row = ci >> 3, gc = (ci & 7) ^ (row & 7);
      glds16(Kg + ((size_t)(b * SEQ + kt + row)) * D_MODEL + h * DKH + gc * 8,
             smem + (size_t)(i * 256 + (tid & 192)) * 16);
    }
    {  // V transpose: key-pairs packed u32, [dk][kp], stride 67
      union { uint4 u; u16 s[8]; } a0, a1, a2, a3;
      a0.u = v0; a1.u = v1; a2.u = v2; a3.u = v3;
#pragma unroll
      for (int j = 0; j < 8; ++j) {
        Vt[dc + j][kp]      = (u32)a0.s[j] | ((u32)a1.s[j] << 16);
        Vt[dc + j][32 + kp] = (u32)a2.s[j] | ((u32)a3.s[j] << 16);
      }
    }
    __syncthreads();                 // also drains glds vmcnt

    // S^T = K_slice * Q^T (pre-scaled), exp2 -> P^T B-frags (registers only)
    f16x4 pb[2][4];
#pragma unroll
    for (int mt = 0; mt < 2; ++mt) {
      const int krow = wave * 32 + mt * 16 + l16;
      const int s0 = quad ^ (krow & 7);
      f16x8 ka0 = *(const f16x8*)(KsL + krow * 64 + s0 * 8);
      f16x8 ka1 = *(const f16x8*)(KsL + krow * 64 + (s0 ^ 4) * 8);
      const int keyb = kt + wave * 32 + mt * 16 + quad * 4;
#pragma unroll
      for (int nt = 0; nt < 4; ++nt) {
        f32x4 c = (f32x4){0.f, 0.f, 0.f, 0.f};
        c = __builtin_amdgcn_mfma_f32_16x16x32_f16(ka0, qf[nt][0], c, 0, 0, 0);
        c = __builtin_amdgcn_mfma_f32_16x16x32_f16(ka1, qf[nt][1], c, 0, 0, 0);
        const int q = q0 + nt * 16 + l16;
        float p0 = __builtin_amdgcn_exp2f(c[0]);
        float p1 = __builtin_amdgcn_exp2f(c[1]);
        float p2 = __builtin_amdgcn_exp2f(c[2]);
        float p3 = __builtin_amdgcn_exp2f(c[3]);
        if (t == nkt - 1) {          // causal mask (only last tile can clip)
          p0 = (keyb + 0 <= q) ? p0 : 0.f;
          p1 = (keyb + 1 <= q) ? p1 : 0.f;
          p2 = (keyb + 2 <= q) ? p2 : 0.f;
          p3 = (keyb + 3 <= q) ? p3 : 0.f;
        }
        lacc[nt] += (p0 + p1) + (p2 + p3);
        union { u32 w[2]; f16x4 v; } pp;
        pp.w[0] = pk(p0, p1); pp.w[1] = pk(p2, p3);
        pb[mt][nt] = pp.v;
      }
    }

    // O^T += V^T_slice * P^T  (16x16x16_f16, k = 16 keys per step)
#pragma unroll
    for (int md = 0; md < 4; ++md)
#pragma unroll
      for (int ks2 = 0; ks2 < 2; ++ks2) {
        const u32* vp = &Vt[md * 16 + l16][wave * 16 + ks2 * 8 + quad * 2];
        union { u32 x[2]; f16x4 v; } va;
        va.x[0] = vp[0]; va.x[1] = vp[1];
#pragma unroll
        for (int nt = 0; nt < 4; ++nt)
          o[md][nt] = __builtin_amdgcn_mfma_f32_16x16x16f16(va.v, pb[ks2][nt], o[md][nt], 0, 0, 0);
      }
  }

  __syncthreads();
  // cross-wave reduction: wave-pairs {0,1}->Red0, {2,3}->Red1; L fully parallel
  {
    float (*Rw)[66] = (wave >= 2) ? Red1 : Red0;
    if ((wave & 1) == 0) {           // waves 0,2 initialize
#pragma unroll
      for (int md = 0; md < 4; ++md)
#pragma unroll
        for (int nt = 0; nt < 4; ++nt)
#pragma unroll
          for (int r = 0; r < 4; ++r)
            Rw[md * 16 + quad * 4 + r][nt * 16 + l16] = o[md][nt][r];
    }
#pragma unroll
    for (int nt = 0; nt < 4; ++nt)
      Lb[nt * 16 + l16][wave * 4 + quad] = lacc[nt];
    __syncthreads();
    if (wave & 1) {                  // waves 1,3 accumulate
#pragma unroll
      for (int md = 0; md < 4; ++md)
#pragma unroll
        for (int nt = 0; nt < 4; ++nt)
#pragma unroll
          for (int r = 0; r < 4; ++r)
            Rw[md * 16 + quad * 4 + r][nt * 16 + l16] += o[md][nt][r];
    }
    __syncthreads();
  }

  // normalize + store: thread -> (q, 16-dk chunk), 32B contiguous
  {
    const int q = tid & 63, dc4 = (tid >> 6) * 16;
    float lsum = 0.f;
#pragma unroll
    for (int j = 0; j < 16; ++j) lsum += Lb[q][j];
    float linv = __builtin_amdgcn_rcpf(lsum);
    union { uint4 u[2]; u32 w[8]; } ov;
#pragma unroll
    for (int i = 0; i < 8; ++i) {
      float f0 = Red0[dc4 + 2 * i][q]     + Red1[dc4 + 2 * i][q];
      float f1 = Red0[dc4 + 2 * i + 1][q] + Red1[dc4 + 2 * i + 1][q];
      ov.w[i] = pk(f0 * linv, f1 * linv);
    }
    f16* op = O + ((size_t)(b * SEQ + q0 + q)) * D_MODEL + h * DKH + dc4;
    *(uint4*)op = ov.u[0];
    *(uint4*)(op + 8) = ov.u[1];
  }
}

// ---------------- launch ----------------
extern "C" void kernel_launch(void* const* d_in, const int* in_sizes, int n_in,
                              void* d_out, int out_size, void* d_ws, size_t ws_size,
                              hipStream_t stream) {
  const float* x      = (const float*)d_in[0];
  const int*   tokpos = (const int*)d_in[1];
  const float* wq     = (const float*)d_in[2];
  const float* wk     = (const float*)d_in[3];
  const float* wv     = (const float*)d_in[4];
  const float* wo     = (const float*)d_in[5];
  float* out = (float*)d_out;

  char* ws = (char*)d_ws;
  f16* Xb  = (f16*)(ws + 0);           // 16 MB (also Ob)
  f16* Wqb = (f16*)(ws + 16777216);    // Wq,Wk,Wv contiguous -> one [3072][1024]
  f16* Wkb = (f16*)(ws + 18874368);
  f16* Wvb = (f16*)(ws + 20971520);
  f16* Wob = (f16*)(ws + 23068672);
  f16* Qb  = (f16*)(ws + 25165824);
  f16* Kb  = (f16*)(ws + 41943040);
  f16* Vb  = (f16*)(ws + 58720256);
  f16* Ob  = Xb;

  cvt_all<<<12288, 256, 0, stream>>>(x, wq, wk, wv, wo, Xb, Wqb, Wkb, Wvb, Wob);

  // fused QKV projection + RoPE: C[8192,3072] = X * Wqkv^T, split to Qb/Kb/Vb
  gemm_glds<1><<<dim3(24, 64), 256, 0, stream>>>(Xb, Wqb, Qb, Kb, Vb, tokpos, D_MODEL);

  flash_attn<<<dim3(BATCH * NH, 32), 256, 0, stream>>>(Qb, Kb, Vb, Ob);

  gemm_glds<0><<<dim3(8, 64), 256, 0, stream>>>(Ob, Wob, out, nullptr, nullptr, nullptr, D_MODEL);
}